// Round 4
// baseline (88.014 us; speedup 1.0000x reference)
//
#include <hip/hip_runtime.h>

#define BB 16384
#define LL 256
#define HH 16
#define LO (-6.0f)
#define HI (6.0f)
#define NI 256        // intervals
#define NE 257        // entries per latent
#define LT 32         // latents per block tile
#define TPB 512       // 8 waves/block -> 4 blocks/CU = 32 waves/CU (max occupancy)
#define SP (TPB / LT) // samples per pass = 16
#define RP 8          // passes; samples per block = SP*RP = 128

static __device__ __forceinline__ float fast_exp2(float x) { return __builtin_amdgcn_exp2f(x); }
static __device__ __forceinline__ float fast_log2(float x) { return __builtin_amdgcn_logf(x); }

// Exact per-latent MLP in base-2 domain (cold fallback for |y| > HI; execz-skipped
// in practice -- N(0,1) inputs essentially never exceed 6 sigma).
static __device__ __forceinline__ float mlp_exact(
    float yv, int l,
    const float* __restrict__ W1, const float* __restrict__ b1,
    const float* __restrict__ W2, const float* __restrict__ b2) {
    const float LOG2E = 1.4426950408889634f;
    float acc2 = b2[l] * LOG2E;
    #pragma unroll 1   // keep cold path compact: minimize register pressure
    for (int h = 0; h < HH; ++h) {
        float x2 = fmaf(yv, W1[l * HH + h] * LOG2E, b1[l * HH + h] * LOG2E);
        float e  = fast_exp2(-fabsf(x2));
        float sp = fmaxf(x2, 0.0f) + fast_log2(1.0f + e);
        acc2 = fmaf(sp, W2[l * HH + h], acc2);
    }
    return __builtin_amdgcn_rcpf(1.0f + fast_exp2(-acc2));
}

// Kernel 1: 4 lanes per LUT entry (4 h-terms each), shfl butterfly reduce.
// 263168*4 threads -> ~16 waves/SIMD queued: hides the trans chain. (~1-2 us)
__global__ __launch_bounds__(256) void build_lut(
    const float* __restrict__ W1, const float* __restrict__ b1,
    const float* __restrict__ W2, const float* __restrict__ b2,
    float* __restrict__ tbl) {
    const float LOG2E = 1.4426950408889634f;
    int gid = blockIdx.x * 256 + threadIdx.x;
    int entry = gid >> 2;                 // (l, i)
    int q = gid & 3;                      // which h-quad
    if (entry >= LL * NE) return;
    int l = entry / NE;
    int i = entry - l * NE;
    float u = LO + (HI - LO) * ((float)i / (float)NI);

    float part = 0.0f;
    #pragma unroll
    for (int hh = 0; hh < 4; ++hh) {
        int h = q * 4 + hh;
        float x2 = fmaf(u, W1[l * HH + h] * LOG2E, b1[l * HH + h] * LOG2E);
        float e  = fast_exp2(-fabsf(x2));
        float sp = fmaxf(x2, 0.0f) + fast_log2(1.0f + e);
        part = fmaf(sp, W2[l * HH + h], part);
    }
    part += __shfl_xor(part, 1, 64);
    part += __shfl_xor(part, 2, 64);      // lanes q=0..3 all hold full sum
    if (q == 0) {
        float acc2 = part + b2[l] * LOG2E;
        tbl[entry] = __builtin_amdgcn_rcpf(1.0f + fast_exp2(-acc2));
    }
}

// Kernel 2: gather + lerp. 512 thr = 32 latents x 16 samples/pass, 8 passes.
// All 8 y loads issued up-front (latency hidden under LDS staging+barrier);
// main loop is pure LDS-lerp + streaming store. Nontemporal y/out keeps L2
// for the tbl slices. lt = blockIdx.x & 7 == XCD id under round-robin
// dispatch -> each XCD's L2 serves one 32.9 KB tbl slice.
__global__ __launch_bounds__(TPB, 8) void lut_kernel(
    const float* __restrict__ y, float* __restrict__ out,
    const float* __restrict__ tbl,
    const float* __restrict__ W1, const float* __restrict__ b1,
    const float* __restrict__ W2, const float* __restrict__ b2) {
    __shared__ float s[LT * NE];                // 32.9 KB -> 4 blocks/CU
    const int lt = blockIdx.x & 7;              // 8 latent tiles
    const int bb = blockIdx.x >> 3;             // 128 sample blocks
    const int l0 = lt * LT;

    const int l_local = threadIdx.x & (LT - 1);
    const int s_idx   = threadIdx.x >> 5;       // 0..15 (sample within pass)
    const int l       = l0 + l_local;
    const int b0      = bb * (SP * RP) + s_idx;

    // Issue ALL y loads before staging: 8 outstanding vmem ops whose latency
    // fully hides under the tbl stage + barrier. Static indexing (rule: no
    // runtime-indexed register arrays).
    float yv[RP];
    #pragma unroll
    for (int r = 0; r < RP; ++r)
        yv[r] = __builtin_nontemporal_load(&y[(b0 + r * SP) * LL + l]);

    // Stage tbl slice as float4: 8224 floats = 2056 float4 (l0*NE*4 bytes is
    // 16B-aligned since l0 % 32 == 0). ds_write_b128, 4x fewer instructions.
    {
        const float4* __restrict__ tv = reinterpret_cast<const float4*>(tbl + l0 * NE);
        float4* __restrict__ sv = reinterpret_cast<float4*>(s);
        for (int j = threadIdx.x; j < (LT * NE) / 4; j += TPB)
            sv[j] = tv[j];                      // coalesced, L2-resident
    }
    __syncthreads();

    const float* __restrict__ srow = s + l_local * NE;  // bank = (l_local+i)%32: conflict-free
    const float SCALE = (float)NI / (HI - LO);

    #pragma unroll
    for (int r = 0; r < RP; ++r) {
        const int b = b0 + r * SP;
        float t = (yv[r] - LO) * SCALE;
        t = fminf(fmaxf(t, 0.0f), (float)NI);
        int i = (int)t;
        i = min(i, NI - 1);
        float fr = t - (float)i;
        float v0 = srow[i];
        float v1 = srow[i + 1];                 // ds_read2_b32 pair
        float res = fmaf(fr, v1 - v0, v0);
        if (__builtin_expect(fabsf(yv[r]) > HI, 0)) {
            res = mlp_exact(yv[r], l, W1, b1, W2, b2);  // execz-skipped
        }
        __builtin_nontemporal_store(res, &out[b * LL + l]);  // coalesced stream
    }
}

extern "C" void kernel_launch(void* const* d_in, const int* in_sizes, int n_in,
                              void* d_out, int out_size, void* d_ws, size_t ws_size,
                              hipStream_t stream) {
    // inputs: 0=t, 1=y [B,L], 2=W1 [L,H], 3=b1 [L,H], 4=W2 [L,H], 5=b2 [L], 6=args
    const float* y  = (const float*)d_in[1];
    const float* W1 = (const float*)d_in[2];
    const float* b1 = (const float*)d_in[3];
    const float* W2 = (const float*)d_in[4];
    const float* b2 = (const float*)d_in[5];
    float* out = (float*)d_out;
    float* tbl = (float*)d_ws;                  // 256*257*4 = 263 KB of workspace

    build_lut<<<(LL * NE * 4 + 255) / 256, 256, 0, stream>>>(W1, b1, W2, b2, tbl);
    lut_kernel<<<8 * (BB / (SP * RP)), TPB, 0, stream>>>(y, out, tbl, W1, b1, W2, b2);
}